// Round 3
// baseline (135.431 us; speedup 1.0000x reference)
//
#include <hip/hip_runtime.h>

#define BB 2
#define LL 16
#define CC 16
#define HH 64
#define WW 64
#define HWSZ (HH * WW)
#define NSEG 36   // per i: ceil(i/4) width-4 (padded) j-segments, i = 1..15

__device__ __constant__ int SEG_I[NSEG] = {
    1, 2, 3, 4,
    5, 5, 6, 6, 7, 7, 8, 8,
    9, 9, 9, 10, 10, 10, 11, 11, 11, 12, 12, 12,
    13, 13, 13, 13, 14, 14, 14, 14, 15, 15, 15, 15};
__device__ __constant__ int SEG_J0[NSEG] = {
    0, 0, 0, 0,
    0, 4, 0, 4, 0, 4, 0, 4,
    0, 4, 8, 0, 4, 8, 0, 4, 8, 0, 4, 8,
    0, 4, 8, 12, 0, 4, 8, 12, 0, 4, 8, 12};

// ---- Kernel A: cumsum of flows along L, into d_ws. All 16 loads independent. ----
__global__ __launch_bounds__(256) void gsp_cumsum(
    const float* __restrict__ flows,  // (B, L, 2, H, W)
    float* __restrict__ cum)          // (B, L, 2, H, W)
{
    const int gid = blockIdx.x * 256 + threadIdx.x;   // 0 .. B*2*HWSZ-1 (16384)
    const int b    = gid / (2 * HWSZ);
    const int r    = gid % (2 * HWSZ);
    const int comp = r / HWSZ;
    const int pix  = r % HWSZ;

    float v[LL];
    #pragma unroll
    for (int l = 0; l < LL; ++l)
        v[l] = flows[((size_t)(b * LL + l) * 2 + comp) * HWSZ + pix];
    #pragma unroll
    for (int l = 1; l < LL; ++l) v[l] += v[l - 1];
    #pragma unroll
    for (int l = 0; l < LL; ++l)
        cum[((size_t)(b * LL + l) * 2 + comp) * HWSZ + pix] = v[l];
}

// ---- Kernel B: identity term (j == i samples land exactly on pixel centers) ----
__global__ __launch_bounds__(256) void gsp_identity(
    const float4* __restrict__ images, float4* __restrict__ out)
{
    const int idx = blockIdx.x * 256 + threadIdx.x;   // 524288 float4s
    out[idx] = images[idx];
}

// ---- Kernel C: all j<i contributions. 4 padded pairs x 8 channels per block. ----
__global__ __launch_bounds__(256) void gsp_pairs(
    const float* __restrict__ cum,     // (B, L, 2, H, W)
    const float* __restrict__ images,  // (B, L, C, H, W)
    float* __restrict__ out)           // (B, L, C, H, W)
{
    const int tile  = blockIdx.x & 15;
    const int seg   = (blockIdx.x >> 4) % NSEG;
    const int rest  = blockIdx.x / (16 * NSEG);
    const int chalf = rest & 1;
    const int b     = rest >> 1;

    const int i  = SEG_I[seg];
    const int j0 = SEG_J0[seg];
    const int jmax = i - 1;

    const int pix = tile * 256 + threadIdx.x;    // 0..4095
    const int h = pix >> 6;
    const int w = pix & (WW - 1);

    const float* img_b = images + (size_t)b * LL * CC * HWSZ + (size_t)chalf * 8 * HWSZ;
    const float* cum_b = cum + (size_t)b * LL * 2 * HWSZ;

    const float gxb = (w + 0.5f) * (2.0f / WW) - 1.0f;
    const float gyb = (h + 0.5f) * (2.0f / HH) - 1.0f;

    const float cix = cum_b[(size_t)i * 2 * HWSZ + pix];
    const float ciy = cum_b[(size_t)i * 2 * HWSZ + HWSZ + pix];

    float acc[8];
    #pragma unroll
    for (int c = 0; c < 8; ++c) acc[c] = 0.0f;

    #pragma unroll
    for (int k = 0; k < 4; ++k) {
        const int jraw = j0 + k;
        const int j = min(jraw, jmax);            // clamp; padded lanes get weight 0
        const float wpad = (jraw <= jmax) ? 1.0f : 0.0f;

        const float cjx = cum_b[(size_t)j * 2 * HWSZ + pix];
        const float cjy = cum_b[(size_t)j * 2 * HWSZ + HWSZ + pix];

        float gx = gxb + (cix - cjx);
        float gy = gyb + (ciy - cjy);

        // gx = remainder(gx + 1, 2) - 1
        float tt = gx + 1.0f;
        tt = tt - floorf(tt * 0.5f) * 2.0f;
        gx = tt - 1.0f;

        const float ix = ((gx + 1.0f) * WW - 1.0f) * 0.5f;
        const float iy = ((gy + 1.0f) * HH - 1.0f) * 0.5f;
        const float x0f = floorf(ix);
        const float y0f = floorf(iy);
        const float wx = ix - x0f;
        const float wy = iy - y0f;
        const int x0 = (int)x0f;
        const int y0 = (int)y0f;
        const int x1 = x0 + 1;
        const int y1 = y0 + 1;

        const bool vx0 = (x0 >= 0) && (x0 < WW);
        const bool vx1 = (x1 >= 0) && (x1 < WW);
        const bool vy0 = (y0 >= 0) && (y0 < HH);
        const bool vy1 = (y1 >= 0) && (y1 < HH);

        const int cx0 = min(max(x0, 0), WW - 1);
        const int cx1 = min(max(x1, 0), WW - 1);
        const int cy0 = min(max(y0, 0), HH - 1);
        const int cy1 = min(max(y1, 0), HH - 1);

        const float w00 = wpad * (1.0f - wx) * (1.0f - wy) * ((vx0 && vy0) ? 1.0f : 0.0f);
        const float w01 = wpad * wx * (1.0f - wy)          * ((vx1 && vy0) ? 1.0f : 0.0f);
        const float w10 = wpad * (1.0f - wx) * wy          * ((vx0 && vy1) ? 1.0f : 0.0f);
        const float w11 = wpad * wx * wy                   * ((vx1 && vy1) ? 1.0f : 0.0f);

        const int o00 = cy0 * WW + cx0;
        const int o01 = cy0 * WW + cx1;
        const int o10 = cy1 * WW + cx0;
        const int o11 = cy1 * WW + cx1;

        const float* jb = img_b + (size_t)j * CC * HWSZ;
        #pragma unroll
        for (int c = 0; c < 8; ++c) {
            const float* p = jb + c * HWSZ;
            acc[c] += w00 * p[o00] + w01 * p[o01] + w10 * p[o10] + w11 * p[o11];
        }
    }

    float* op = out + ((size_t)b * LL + i) * CC * HWSZ + (size_t)chalf * 8 * HWSZ + pix;
    #pragma unroll
    for (int c = 0; c < 8; ++c) atomicAdd(op + c * HWSZ, acc[c]);
}

extern "C" void kernel_launch(void* const* d_in, const int* in_sizes, int n_in,
                              void* d_out, int out_size, void* d_ws, size_t ws_size,
                              hipStream_t stream) {
    const float* flows  = (const float*)d_in[0];
    const float* images = (const float*)d_in[1];
    float* out = (float*)d_out;
    float* cum = (float*)d_ws;                       // B*L*2*HWSZ floats = 1 MB

    gsp_cumsum<<<BB * 2 * HWSZ / 256, 256, 0, stream>>>(flows, cum);

    const int n4 = BB * LL * CC * HWSZ / 4;          // 524288 float4s
    gsp_identity<<<n4 / 256, 256, 0, stream>>>((const float4*)images, (float4*)out);

    const int grid = BB * 2 * NSEG * 16;             // 2304 blocks
    gsp_pairs<<<grid, 256, 0, stream>>>(cum, images, out);
}

// Round 4
// 94.268 us; speedup vs baseline: 1.4367x; 1.4367x over previous
//
#include <hip/hip_runtime.h>

#define BB 2
#define LL 16
#define CC 16
#define HH 64
#define WW 64
#define HWSZ (HH * WW)
#define NSEG 36   // per i: ceil(i/4) width-4 (padded) j-segments, i = 1..15

__device__ __constant__ int SEG_I[NSEG] = {
    1, 2, 3, 4,
    5, 5, 6, 6, 7, 7, 8, 8,
    9, 9, 9, 10, 10, 10, 11, 11, 11, 12, 12, 12,
    13, 13, 13, 13, 14, 14, 14, 14, 15, 15, 15, 15};
__device__ __constant__ int SEG_J0[NSEG] = {
    0, 0, 0, 0,
    0, 4, 0, 4, 0, 4, 0, 4,
    0, 4, 8, 0, 4, 8, 0, 4, 8, 0, 4, 8,
    0, 4, 8, 12, 0, 4, 8, 12, 0, 4, 8, 12};

// ---- Kernel A: cumsum of flows along L -> ws[0 .. 1MB). 16 independent loads. ----
__global__ __launch_bounds__(256) void gsp_cumsum(
    const float* __restrict__ flows,  // (B, L, 2, H, W)
    float* __restrict__ cum)          // (B, L, 2, H, W)
{
    const int gid = blockIdx.x * 256 + threadIdx.x;   // 0 .. B*2*HWSZ-1 (16384)
    const int b    = gid / (2 * HWSZ);
    const int r    = gid % (2 * HWSZ);
    const int comp = r / HWSZ;
    const int pix  = r % HWSZ;

    float v[LL];
    #pragma unroll
    for (int l = 0; l < LL; ++l)
        v[l] = flows[((size_t)(b * LL + l) * 2 + comp) * HWSZ + pix];
    #pragma unroll
    for (int l = 1; l < LL; ++l) v[l] += v[l - 1];
    #pragma unroll
    for (int l = 0; l < LL; ++l)
        cum[((size_t)(b * LL + l) * 2 + comp) * HWSZ + pix] = v[l];
}

// ---- Kernel T: NCHW -> NHWC transpose of images into ws[1MB .. 9MB) ----
// nhwc[(bl*HWSZ + pix)*CC + c] = images[(bl*CC + c)*HWSZ + pix]
__global__ __launch_bounds__(256) void gsp_transpose(
    const float* __restrict__ images, float4* __restrict__ nhwc)
{
    const int gid  = blockIdx.x * 256 + threadIdx.x;  // 0 .. B*L*HWSZ*4-1 (524288)
    const int quad = gid & 3;
    const int pix  = (gid >> 2) & (HWSZ - 1);
    const int bl   = gid >> 14;

    const float* src = images + (size_t)(bl * CC + quad * 4) * HWSZ + pix;
    float4 v;
    v.x = src[0 * HWSZ];
    v.y = src[1 * HWSZ];
    v.z = src[2 * HWSZ];
    v.w = src[3 * HWSZ];
    nhwc[(size_t)(bl * HWSZ + pix) * 4 + quad] = v;
}

// ---- Kernel B: identity term (j == i samples land exactly on pixel centers) ----
__global__ __launch_bounds__(256) void gsp_identity(
    const float4* __restrict__ images, float4* __restrict__ out)
{
    const int idx = blockIdx.x * 256 + threadIdx.x;   // 524288 float4s
    out[idx] = images[idx];
}

// ---- Kernel C: all j<i contributions. Lane = (pixel, channel-quad), float4 gathers
//      from NHWC so the 4 quads of one pixel share a single 64B line. ----
__global__ __launch_bounds__(256) void gsp_pairs(
    const float* __restrict__ cum,     // (B, L, 2, H, W)
    const float* __restrict__ nhwc,    // (B, L, H, W, C)
    float* __restrict__ out)           // (B, L, C, H, W)
{
    const int tile = blockIdx.x & 63;            // 64 tiles of 64 pixels
    const int seg  = (blockIdx.x >> 6) % NSEG;
    const int b    = blockIdx.x / (64 * NSEG);

    const int i    = SEG_I[seg];
    const int j0   = SEG_J0[seg];
    const int jmax = i - 1;

    const int psub = threadIdx.x >> 2;           // 0..63
    const int quad = threadIdx.x & 3;            // channel quad
    const int pix  = tile * 64 + psub;           // 0..4095
    const int h = pix >> 6;
    const int w = pix & (WW - 1);

    const float* cum_b  = cum + (size_t)b * LL * 2 * HWSZ;
    const float* nhwc_b = nhwc + (size_t)b * LL * HWSZ * CC;

    const float gxb = (w + 0.5f) * (2.0f / WW) - 1.0f;
    const float gyb = (h + 0.5f) * (2.0f / HH) - 1.0f;

    const float cix = cum_b[(size_t)i * 2 * HWSZ + pix];
    const float ciy = cum_b[(size_t)i * 2 * HWSZ + HWSZ + pix];

    float ax = 0.0f, ay = 0.0f, az = 0.0f, aw = 0.0f;

    #pragma unroll
    for (int k = 0; k < 4; ++k) {
        const int jraw = j0 + k;
        const int j = min(jraw, jmax);            // clamp; padded lanes weight 0
        const float wpad = (jraw <= jmax) ? 1.0f : 0.0f;

        const float cjx = cum_b[(size_t)j * 2 * HWSZ + pix];
        const float cjy = cum_b[(size_t)j * 2 * HWSZ + HWSZ + pix];

        float gx = gxb + (cix - cjx);
        float gy = gyb + (ciy - cjy);

        // gx = remainder(gx + 1, 2) - 1
        float tt = gx + 1.0f;
        tt = tt - floorf(tt * 0.5f) * 2.0f;
        gx = tt - 1.0f;

        const float ix = ((gx + 1.0f) * WW - 1.0f) * 0.5f;
        const float iy = ((gy + 1.0f) * HH - 1.0f) * 0.5f;
        const float x0f = floorf(ix);
        const float y0f = floorf(iy);
        const float fx = ix - x0f;
        const float fy = iy - y0f;
        const int x0 = (int)x0f;
        const int y0 = (int)y0f;
        const int x1 = x0 + 1;
        const int y1 = y0 + 1;

        const bool vx0 = (x0 >= 0) && (x0 < WW);
        const bool vx1 = (x1 >= 0) && (x1 < WW);
        const bool vy0 = (y0 >= 0) && (y0 < HH);
        const bool vy1 = (y1 >= 0) && (y1 < HH);

        const int cx0 = min(max(x0, 0), WW - 1);
        const int cx1 = min(max(x1, 0), WW - 1);
        const int cy0 = min(max(y0, 0), HH - 1);
        const int cy1 = min(max(y1, 0), HH - 1);

        const float w00 = wpad * (1.0f - fx) * (1.0f - fy) * ((vx0 && vy0) ? 1.0f : 0.0f);
        const float w01 = wpad * fx * (1.0f - fy)          * ((vx1 && vy0) ? 1.0f : 0.0f);
        const float w10 = wpad * (1.0f - fx) * fy          * ((vx0 && vy1) ? 1.0f : 0.0f);
        const float w11 = wpad * fx * fy                   * ((vx1 && vy1) ? 1.0f : 0.0f);

        const int o00 = cy0 * WW + cx0;
        const int o01 = cy0 * WW + cx1;
        const int o10 = cy1 * WW + cx0;
        const int o11 = cy1 * WW + cx1;

        const float4* jb = (const float4*)(nhwc_b + (size_t)j * HWSZ * CC);
        const float4 v00 = jb[o00 * 4 + quad];
        const float4 v01 = jb[o01 * 4 + quad];
        const float4 v10 = jb[o10 * 4 + quad];
        const float4 v11 = jb[o11 * 4 + quad];

        ax += w00 * v00.x + w01 * v01.x + w10 * v10.x + w11 * v11.x;
        ay += w00 * v00.y + w01 * v01.y + w10 * v10.y + w11 * v11.y;
        az += w00 * v00.z + w01 * v01.z + w10 * v10.z + w11 * v11.z;
        aw += w00 * v00.w + w01 * v01.w + w10 * v10.w + w11 * v11.w;
    }

    float* op = out + ((size_t)(b * LL + i) * CC + quad * 4) * HWSZ + pix;
    atomicAdd(op + 0 * HWSZ, ax);
    atomicAdd(op + 1 * HWSZ, ay);
    atomicAdd(op + 2 * HWSZ, az);
    atomicAdd(op + 3 * HWSZ, aw);
}

extern "C" void kernel_launch(void* const* d_in, const int* in_sizes, int n_in,
                              void* d_out, int out_size, void* d_ws, size_t ws_size,
                              hipStream_t stream) {
    const float* flows  = (const float*)d_in[0];
    const float* images = (const float*)d_in[1];
    float* out = (float*)d_out;
    float* cum  = (float*)d_ws;                       // 262144 floats = 1 MB
    float* nhwc = (float*)d_ws + (BB * LL * 2 * HWSZ); // 2097152 floats = 8 MB

    gsp_cumsum<<<BB * 2 * HWSZ / 256, 256, 0, stream>>>(flows, cum);

    gsp_transpose<<<BB * LL * HWSZ * 4 / 256, 256, 0, stream>>>(images, (float4*)nhwc);

    const int n4 = BB * LL * CC * HWSZ / 4;           // 524288 float4s
    gsp_identity<<<n4 / 256, 256, 0, stream>>>((const float4*)images, (float4*)out);

    const int grid = BB * NSEG * 64;                  // 4608 blocks
    gsp_pairs<<<grid, 256, 0, stream>>>(cum, nhwc, out);
}

// Round 5
// 91.839 us; speedup vs baseline: 1.4747x; 1.0265x over previous
//
#include <hip/hip_runtime.h>

#define BB 2
#define LL 16
#define CC 16
#define HH 64
#define WW 64
#define HWSZ (HH * WW)
#define NSEG 36   // per i: ceil(i/4) width-4 (padded) j-segments, i = 1..15

__device__ __constant__ int SEG_I[NSEG] = {
    1, 2, 3, 4,
    5, 5, 6, 6, 7, 7, 8, 8,
    9, 9, 9, 10, 10, 10, 11, 11, 11, 12, 12, 12,
    13, 13, 13, 13, 14, 14, 14, 14, 15, 15, 15, 15};
__device__ __constant__ int SEG_J0[NSEG] = {
    0, 0, 0, 0,
    0, 4, 0, 4, 0, 4, 0, 4,
    0, 4, 8, 0, 4, 8, 0, 4, 8, 0, 4, 8,
    0, 4, 8, 12, 0, 4, 8, 12, 0, 4, 8, 12};

// ws layout: [0, 1MB) cum2 as (B, L, HW, 2) float2; [1MB, 9MB) NHWC images
#define CUM2_FLOATS (BB * LL * HWSZ * 2)   // 262144

// ---- Fused prep kernel ----
// blocks [0,32):        cumsum of flows -> cum2 (float2-interleaved)
// blocks [32, 32+2048): NCHW->NHWC transpose AND identity-term write to out
__global__ __launch_bounds__(256) void gsp_prep(
    const float* __restrict__ flows,   // (B, L, 2, H, W)
    const float* __restrict__ images,  // (B, L, C, H, W)
    float2* __restrict__ cum2,         // (B, L, HW) float2
    float4* __restrict__ nhwc,         // (B, L, HW, C) as float4 quads
    float* __restrict__ out)           // (B, L, C, H, W)
{
    if (blockIdx.x < 32) {
        // cumsum: thread = (b, pix), both components, 32 independent loads
        const int gid = blockIdx.x * 256 + threadIdx.x;   // 0..8191
        const int b   = gid >> 12;
        const int pix = gid & (HWSZ - 1);
        const float* fb = flows + (size_t)b * LL * 2 * HWSZ + pix;
        float vx[LL], vy[LL];
        #pragma unroll
        for (int l = 0; l < LL; ++l) {
            vx[l] = fb[(size_t)l * 2 * HWSZ];
            vy[l] = fb[(size_t)l * 2 * HWSZ + HWSZ];
        }
        #pragma unroll
        for (int l = 1; l < LL; ++l) { vx[l] += vx[l - 1]; vy[l] += vy[l - 1]; }
        float2* cb = cum2 + (size_t)b * LL * HWSZ + pix;
        #pragma unroll
        for (int l = 0; l < LL; ++l) {
            float2 v; v.x = vx[l]; v.y = vy[l];
            cb[(size_t)l * HWSZ] = v;
        }
    } else {
        // transpose + identity: thread = (bl, pix, quad)
        const int gid  = (blockIdx.x - 32) * 256 + threadIdx.x;  // 0..524287
        const int quad = gid & 3;
        const int pix  = (gid >> 2) & (HWSZ - 1);
        const int bl   = gid >> 14;

        const float* src = images + (size_t)(bl * CC + quad * 4) * HWSZ + pix;
        float4 v;
        v.x = src[0 * HWSZ];
        v.y = src[1 * HWSZ];
        v.z = src[2 * HWSZ];
        v.w = src[3 * HWSZ];
        nhwc[(size_t)(bl * HWSZ + pix) * 4 + quad] = v;

        // identity term: out[bl, quad*4 + c, pix] = images[...]  (j == i samples
        // land exactly on integer pixel centers -> pure copy)
        float* op = out + (size_t)(bl * CC + quad * 4) * HWSZ + pix;
        op[0 * HWSZ] = v.x;
        op[1 * HWSZ] = v.y;
        op[2 * HWSZ] = v.z;
        op[3 * HWSZ] = v.w;
    }
}

// ---- Pairs kernel: all j<i contributions. Lane = (pixel, channel-quad); float4
//      gathers from NHWC so one pixel's 4 quads share a single 64B line. ----
__global__ __launch_bounds__(256) void gsp_pairs(
    const float2* __restrict__ cum2,   // (B, L, HW) float2
    const float* __restrict__ nhwc,    // (B, L, HW, C)
    float* __restrict__ out)           // (B, L, C, H, W)
{
    const int tile = blockIdx.x & 63;            // 64 tiles of 64 pixels
    const int seg  = (blockIdx.x >> 6) % NSEG;
    const int b    = blockIdx.x / (64 * NSEG);

    const int i    = SEG_I[seg];
    const int j0   = SEG_J0[seg];
    const int jmax = i - 1;

    const int psub = threadIdx.x >> 2;           // 0..63
    const int quad = threadIdx.x & 3;            // channel quad
    const int pix  = tile * 64 + psub;           // 0..4095
    const int h = pix >> 6;
    const int w = pix & (WW - 1);

    const float2* cum_b = cum2 + (size_t)b * LL * HWSZ + pix;
    const float* nhwc_b = nhwc + (size_t)b * LL * HWSZ * CC;

    const float gxb = (w + 0.5f) * (2.0f / WW) - 1.0f;
    const float gyb = (h + 0.5f) * (2.0f / HH) - 1.0f;

    const float2 ci = cum_b[(size_t)i * HWSZ];

    float ax = 0.0f, ay = 0.0f, az = 0.0f, aw = 0.0f;

    #pragma unroll
    for (int k = 0; k < 4; ++k) {
        const int jraw = j0 + k;
        const int j = min(jraw, jmax);            // clamp; padded lanes weight 0
        const float wpad = (jraw <= jmax) ? 1.0f : 0.0f;

        const float2 cj = cum_b[(size_t)j * HWSZ];

        float gx = gxb + (ci.x - cj.x);
        float gy = gyb + (ci.y - cj.y);

        // gx = remainder(gx + 1, 2) - 1
        float tt = gx + 1.0f;
        tt = tt - floorf(tt * 0.5f) * 2.0f;
        gx = tt - 1.0f;

        const float ix = ((gx + 1.0f) * WW - 1.0f) * 0.5f;
        const float iy = ((gy + 1.0f) * HH - 1.0f) * 0.5f;
        const float x0f = floorf(ix);
        const float y0f = floorf(iy);
        const float fx = ix - x0f;
        const float fy = iy - y0f;
        const int x0 = (int)x0f;
        const int y0 = (int)y0f;
        const int x1 = x0 + 1;
        const int y1 = y0 + 1;

        const bool vx0 = (x0 >= 0) && (x0 < WW);
        const bool vx1 = (x1 >= 0) && (x1 < WW);
        const bool vy0 = (y0 >= 0) && (y0 < HH);
        const bool vy1 = (y1 >= 0) && (y1 < HH);

        const int cx0 = min(max(x0, 0), WW - 1);
        const int cx1 = min(max(x1, 0), WW - 1);
        const int cy0 = min(max(y0, 0), HH - 1);
        const int cy1 = min(max(y1, 0), HH - 1);

        const float w00 = wpad * (1.0f - fx) * (1.0f - fy) * ((vx0 && vy0) ? 1.0f : 0.0f);
        const float w01 = wpad * fx * (1.0f - fy)          * ((vx1 && vy0) ? 1.0f : 0.0f);
        const float w10 = wpad * (1.0f - fx) * fy          * ((vx0 && vy1) ? 1.0f : 0.0f);
        const float w11 = wpad * fx * fy                   * ((vx1 && vy1) ? 1.0f : 0.0f);

        const int o00 = cy0 * WW + cx0;
        const int o01 = cy0 * WW + cx1;
        const int o10 = cy1 * WW + cx0;
        const int o11 = cy1 * WW + cx1;

        const float4* jb = (const float4*)(nhwc_b + (size_t)j * HWSZ * CC);
        const float4 v00 = jb[o00 * 4 + quad];
        const float4 v01 = jb[o01 * 4 + quad];
        const float4 v10 = jb[o10 * 4 + quad];
        const float4 v11 = jb[o11 * 4 + quad];

        ax += w00 * v00.x + w01 * v01.x + w10 * v10.x + w11 * v11.x;
        ay += w00 * v00.y + w01 * v01.y + w10 * v10.y + w11 * v11.y;
        az += w00 * v00.z + w01 * v01.z + w10 * v10.z + w11 * v11.z;
        aw += w00 * v00.w + w01 * v01.w + w10 * v10.w + w11 * v11.w;
    }

    float* op = out + ((size_t)(b * LL + i) * CC + quad * 4) * HWSZ + pix;
    atomicAdd(op + 0 * HWSZ, ax);
    atomicAdd(op + 1 * HWSZ, ay);
    atomicAdd(op + 2 * HWSZ, az);
    atomicAdd(op + 3 * HWSZ, aw);
}

extern "C" void kernel_launch(void* const* d_in, const int* in_sizes, int n_in,
                              void* d_out, int out_size, void* d_ws, size_t ws_size,
                              hipStream_t stream) {
    const float* flows  = (const float*)d_in[0];
    const float* images = (const float*)d_in[1];
    float* out = (float*)d_out;
    float2* cum2 = (float2*)d_ws;                       // 1 MB
    float*  nhwc = (float*)d_ws + CUM2_FLOATS;          // 8 MB

    // prep: 32 cumsum blocks + 2048 transpose/identity blocks
    gsp_prep<<<32 + 2048, 256, 0, stream>>>(flows, images, cum2, (float4*)nhwc, out);

    // pairs: one block per (b, seg, 64-pixel tile)
    const int grid = BB * NSEG * 64;                    // 4608 blocks
    gsp_pairs<<<grid, 256, 0, stream>>>(cum2, nhwc, out);
}

// Round 6
// 91.619 us; speedup vs baseline: 1.4782x; 1.0024x over previous
//
#include <hip/hip_runtime.h>

#define BB 2
#define LL 16
#define CC 16
#define HH 64
#define WW 64
#define HWSZ (HH * WW)
#define NSEG 36   // per i: ceil(i/4) width-4 (padded) j-segments, i = 1..15

__device__ __constant__ int SEG_I[NSEG] = {
    1, 2, 3, 4,
    5, 5, 6, 6, 7, 7, 8, 8,
    9, 9, 9, 10, 10, 10, 11, 11, 11, 12, 12, 12,
    13, 13, 13, 13, 14, 14, 14, 14, 15, 15, 15, 15};
__device__ __constant__ int SEG_J0[NSEG] = {
    0, 0, 0, 0,
    0, 4, 0, 4, 0, 4, 0, 4,
    0, 4, 8, 0, 4, 8, 0, 4, 8, 0, 4, 8,
    0, 4, 8, 12, 0, 4, 8, 12, 0, 4, 8, 12};

// ws layout: [0, 1MB) cum2 as (B, L, HW) float2; [1MB, 9MB) NHWC images
#define CUM2_FLOATS (BB * LL * HWSZ * 2)   // 262144

// ---- Fused prep kernel ----
// blocks [0,32):        cumsum of flows -> cum2 (float2-interleaved)
// blocks [32, 32+2048): NCHW->NHWC transpose AND identity-term write to out
__global__ __launch_bounds__(256) void gsp_prep(
    const float* __restrict__ flows,   // (B, L, 2, H, W)
    const float* __restrict__ images,  // (B, L, C, H, W)
    float2* __restrict__ cum2,         // (B, L, HW) float2
    float4* __restrict__ nhwc,         // (B, L, HW, C) as float4 quads
    float* __restrict__ out)           // (B, L, C, H, W)
{
    if (blockIdx.x < 32) {
        const int gid = blockIdx.x * 256 + threadIdx.x;   // 0..8191
        const int b   = gid >> 12;
        const int pix = gid & (HWSZ - 1);
        const float* fb = flows + (size_t)b * LL * 2 * HWSZ + pix;
        float vx[LL], vy[LL];
        #pragma unroll
        for (int l = 0; l < LL; ++l) {
            vx[l] = fb[(size_t)l * 2 * HWSZ];
            vy[l] = fb[(size_t)l * 2 * HWSZ + HWSZ];
        }
        #pragma unroll
        for (int l = 1; l < LL; ++l) { vx[l] += vx[l - 1]; vy[l] += vy[l - 1]; }
        float2* cb = cum2 + (size_t)b * LL * HWSZ + pix;
        #pragma unroll
        for (int l = 0; l < LL; ++l) {
            float2 v; v.x = vx[l]; v.y = vy[l];
            cb[(size_t)l * HWSZ] = v;
        }
    } else {
        const int gid  = (blockIdx.x - 32) * 256 + threadIdx.x;  // 0..524287
        const int quad = gid & 3;
        const int pix  = (gid >> 2) & (HWSZ - 1);
        const int bl   = gid >> 14;

        const float* src = images + (size_t)(bl * CC + quad * 4) * HWSZ + pix;
        float4 v;
        v.x = src[0 * HWSZ];
        v.y = src[1 * HWSZ];
        v.z = src[2 * HWSZ];
        v.w = src[3 * HWSZ];
        nhwc[(size_t)(bl * HWSZ + pix) * 4 + quad] = v;

        // identity term (j == i samples land exactly on integer pixel centers)
        float* op = out + (size_t)(bl * CC + quad * 4) * HWSZ + pix;
        op[0 * HWSZ] = v.x;
        op[1 * HWSZ] = v.y;
        op[2 * HWSZ] = v.z;
        op[3 * HWSZ] = v.w;
    }
}

// ---- Pairs kernel: all j<i contributions. Lane = (pixel, channel-quad).
//      Explicit phase structure: all 16 gather addresses first, then 16
//      independent float4 loads IN FLIGHT TOGETHER, weights computed under
//      the loads, then FMA-reduce. This is the MLP the 32-VGPR version lacked. ----
__global__ __launch_bounds__(256) void gsp_pairs(
    const float2* __restrict__ cum2,   // (B, L, HW) float2
    const float4* __restrict__ nhwc,   // (B, L, HW, 4) float4 quads
    float* __restrict__ out)           // (B, L, C, H, W)
{
    const int tile = blockIdx.x & 63;            // 64 tiles of 64 pixels
    const int seg  = (blockIdx.x >> 6) % NSEG;
    const int b    = blockIdx.x / (64 * NSEG);

    const int i    = SEG_I[seg];
    const int j0   = SEG_J0[seg];
    const int jmax = i - 1;

    const int psub = threadIdx.x >> 2;           // 0..63
    const int quad = threadIdx.x & 3;            // channel quad
    const int pix  = tile * 64 + psub;           // 0..4095
    const int h = pix >> 6;
    const int w = pix & (WW - 1);

    const float2* cum_b  = cum2 + (size_t)b * LL * HWSZ + pix;
    const float4* nhwc_b = nhwc + (size_t)b * LL * HWSZ * 4;

    const float gxb = (w + 0.5f) * (2.0f / WW) - 1.0f;
    const float gyb = (h + 0.5f) * (2.0f / HH) - 1.0f;

    // ---- phase 1: cum loads (5 independent) ----
    const float2 ci = cum_b[(size_t)i * HWSZ];
    int   jj[4];
    float2 cj[4];
    #pragma unroll
    for (int k = 0; k < 4; ++k) {
        jj[k] = min(j0 + k, jmax);
        cj[k] = cum_b[(size_t)jj[k] * HWSZ];
    }

    // ---- phase 2: addresses (int-only path to the gathers) + fractional parts ----
    int   off[16];
    float fxk[4], fyk[4];
    float m00[4], m01[4], m10[4], m11[4];   // validity masks (as floats)
    #pragma unroll
    for (int k = 0; k < 4; ++k) {
        float gx = gxb + (ci.x - cj[k].x);
        float gy = gyb + (ci.y - cj[k].y);

        // gx = remainder(gx + 1, 2) - 1
        float tt = gx + 1.0f;
        tt = tt - floorf(tt * 0.5f) * 2.0f;
        gx = tt - 1.0f;

        const float ix = ((gx + 1.0f) * WW - 1.0f) * 0.5f;
        const float iy = ((gy + 1.0f) * HH - 1.0f) * 0.5f;
        const float x0f = floorf(ix);
        const float y0f = floorf(iy);
        fxk[k] = ix - x0f;
        fyk[k] = iy - y0f;
        const int x0 = (int)x0f;
        const int y0 = (int)y0f;
        const int x1 = x0 + 1;
        const int y1 = y0 + 1;

        const bool vx0 = (x0 >= 0) && (x0 < WW);
        const bool vx1 = (x1 >= 0) && (x1 < WW);
        const bool vy0 = (y0 >= 0) && (y0 < HH);
        const bool vy1 = (y1 >= 0) && (y1 < HH);
        const float wpad = (j0 + k <= jmax) ? 1.0f : 0.0f;
        m00[k] = (vx0 && vy0) ? wpad : 0.0f;
        m01[k] = (vx1 && vy0) ? wpad : 0.0f;
        m10[k] = (vx0 && vy1) ? wpad : 0.0f;
        m11[k] = (vx1 && vy1) ? wpad : 0.0f;

        const int cx0 = min(max(x0, 0), WW - 1);
        const int cx1 = min(max(x1, 0), WW - 1);
        const int cy0 = min(max(y0, 0), HH - 1);
        const int cy1 = min(max(y1, 0), HH - 1);

        const int jbase = jj[k] * (HWSZ * 4) + quad;   // float4 units
        off[k * 4 + 0] = jbase + (cy0 * WW + cx0) * 4;
        off[k * 4 + 1] = jbase + (cy0 * WW + cx1) * 4;
        off[k * 4 + 2] = jbase + (cy1 * WW + cx0) * 4;
        off[k * 4 + 3] = jbase + (cy1 * WW + cx1) * 4;
    }

    // ---- phase 3: 16 independent gathers, all in flight together ----
    float4 v[16];
    #pragma unroll
    for (int m = 0; m < 16; ++m) v[m] = nhwc_b[off[m]];

    // ---- phase 4: weights (computed while gathers are in flight) ----
    float wgt[16];
    #pragma unroll
    for (int k = 0; k < 4; ++k) {
        const float fx = fxk[k], fy = fyk[k];
        wgt[k * 4 + 0] = m00[k] * (1.0f - fx) * (1.0f - fy);
        wgt[k * 4 + 1] = m01[k] * fx * (1.0f - fy);
        wgt[k * 4 + 2] = m10[k] * (1.0f - fx) * fy;
        wgt[k * 4 + 3] = m11[k] * fx * fy;
    }

    // ---- phase 5: FMA reduce ----
    float ax = 0.0f, ay = 0.0f, az = 0.0f, aw = 0.0f;
    #pragma unroll
    for (int m = 0; m < 16; ++m) {
        ax += wgt[m] * v[m].x;
        ay += wgt[m] * v[m].y;
        az += wgt[m] * v[m].z;
        aw += wgt[m] * v[m].w;
    }

    float* op = out + ((size_t)(b * LL + i) * CC + quad * 4) * HWSZ + pix;
    atomicAdd(op + 0 * HWSZ, ax);
    atomicAdd(op + 1 * HWSZ, ay);
    atomicAdd(op + 2 * HWSZ, az);
    atomicAdd(op + 3 * HWSZ, aw);
}

extern "C" void kernel_launch(void* const* d_in, const int* in_sizes, int n_in,
                              void* d_out, int out_size, void* d_ws, size_t ws_size,
                              hipStream_t stream) {
    const float* flows  = (const float*)d_in[0];
    const float* images = (const float*)d_in[1];
    float* out = (float*)d_out;
    float2* cum2 = (float2*)d_ws;                       // 1 MB
    float*  nhwc = (float*)d_ws + CUM2_FLOATS;          // 8 MB

    gsp_prep<<<32 + 2048, 256, 0, stream>>>(flows, images, cum2, (float4*)nhwc, out);

    const int grid = BB * NSEG * 64;                    // 4608 blocks
    gsp_pairs<<<grid, 256, 0, stream>>>(cum2, (const float4*)nhwc, out);
}